// Round 9
// baseline (529.181 us; speedup 1.0000x reference)
//
#include <hip/hip_runtime.h>
#include <hip/hip_bf16.h>

#define NN 50000
#define HH 4
#define RR 3
#define EE 524288      // 2^19
#define ESHIFT 19
#define TN (RR*NN)     // 150000
#define NCHUNK ((TN + 1023)/1024)  // 147
#define LOG2E 1.4426950408889634f

// Pipeline split row (tile-aligned, < NN/2 so GEMM2-h0 writes stay in stripe lower halves)
#define SPLIT 24960

typedef __attribute__((ext_vector_type(8))) short short8;
typedef __attribute__((ext_vector_type(4))) short short4v;
typedef __attribute__((ext_vector_type(4))) float float4v;
typedef __attribute__((ext_vector_type(2))) float float2v;
typedef __attribute__((ext_vector_type(2))) _Float16 half2v;

#if defined(__has_builtin)
#if __has_builtin(__builtin_amdgcn_fdot2)
#define USE_FDOT2 1
#else
#define USE_FDOT2 0
#endif
#else
#define USE_FDOT2 0
#endif

// ---------------- merged prep: conv + 4 weight transposes + hist ----------------

__device__ inline void tw_body(const float* __restrict__ W, __hip_bfloat16* __restrict__ T,
                               int ncs, int colOff, int i) {
    int r = i >> (7 + ncs);
    int rem = i & ((128 << ncs) - 1);
    int k = rem >> ncs;
    int n = rem & ((1 << ncs) - 1);
    T[(size_t)((r << (1 + ncs)) + colOff + n) * 128 + k] = __float2bfloat16(W[i]);
}

__launch_bounds__(256)
__global__ void prep_kernel(const float* __restrict__ x, short4v* __restrict__ xb,
                            const float* __restrict__ W1s, const float* __restrict__ W1d,
                            const float* __restrict__ W2s, const float* __restrict__ W2d,
                            __hip_bfloat16* __restrict__ T1, __hip_bfloat16* __restrict__ T2,
                            const int* __restrict__ dst, int* __restrict__ deg) {
    int wg = blockIdx.x, t = threadIdx.x;
    if (wg < 6250) {                       // conv: NN*128/4 = 1.6M elems, exact
        int i = wg * 256 + t;
        float4v v = ((const float4v*)x)[i];
        short4v o;
        o.x = (short)__bfloat16_as_ushort(__float2bfloat16(v.x));
        o.y = (short)__bfloat16_as_ushort(__float2bfloat16(v.y));
        o.z = (short)__bfloat16_as_ushort(__float2bfloat16(v.z));
        o.w = (short)__bfloat16_as_ushort(__float2bfloat16(v.w));
        xb[i] = o;
    } else if (wg < 6442) {                // W1s: 3*128*128 = 192 blocks exact
        tw_body(W1s, T1, 7, 0, (wg - 6250) * 256 + t);
    } else if (wg < 6634) {                // W1d
        tw_body(W1d, T1, 7, 128, (wg - 6442) * 256 + t);
    } else if (wg < 7018) {                // W2s: 3*128*256 = 384 blocks exact
        tw_body(W2s, T2, 8, 0, (wg - 6634) * 256 + t);
    } else if (wg < 7402) {                // W2d
        tw_body(W2d, T2, 8, 256, (wg - 7018) * 256 + t);
    } else {                               // hist: 3E/256 = 6144 blocks exact
        int i = (wg - 7402) * 256 + t;
        int r = i >> ESHIFT;
        atomicAdd(&deg[r * NN + dst[i]], 1);
    }
}

// ---------------- CSR scan: proven 3-kernel chain ----------------

__global__ void scan1_kernel(const int* __restrict__ deg, int* __restrict__ part) {
    __shared__ int s[256];
    int t = threadIdx.x;
    int base = blockIdx.x * 1024 + t * 4;
    int sum = 0;
#pragma unroll
    for (int j = 0; j < 4; j++) {
        int idx = base + j;
        sum += (idx < TN) ? deg[idx] : 0;
    }
    s[t] = sum;
    __syncthreads();
    for (int off = 128; off > 0; off >>= 1) {
        if (t < off) s[t] += s[t + off];
        __syncthreads();
    }
    if (t == 0) part[blockIdx.x] = s[0];
}

__global__ void scan2_kernel(int* part) {
    int run = 0;
    for (int i = 0; i < NCHUNK; i++) {
        int v = part[i];
        part[i] = run;
        run += v;
    }
}

__global__ void scan3_kernel(const int* __restrict__ deg, const int* __restrict__ part,
                             int* __restrict__ offs, int* __restrict__ curs) {
    __shared__ int s[256];
    int t = threadIdx.x;
    int base = blockIdx.x * 1024 + t * 4;
    int v[4];
    int tsum = 0;
#pragma unroll
    for (int j = 0; j < 4; j++) {
        int idx = base + j;
        v[j] = (idx < TN) ? deg[idx] : 0;
        tsum += v[j];
    }
    s[t] = tsum;
    __syncthreads();
    for (int off = 1; off < 256; off <<= 1) {
        int x = (t >= off) ? s[t - off] : 0;
        __syncthreads();
        s[t] += x;
        __syncthreads();
    }
    int excl = s[t] - tsum + part[blockIdx.x];
    int run = excl;
#pragma unroll
    for (int j = 0; j < 4; j++) {
        int idx = base + j;
        if (idx < TN) {
            offs[idx] = run;
            curs[idx] = run;
            run += v[j];
        }
    }
}

// ---------------- GEMM body ----------------
// Stripe layout: 6 stripes of M*256 f16 elems (25.6 MB). L2 table t = full stripe t
// (tblOff=0). L1 table t = UPPER HALF of stripe t (tblOff=M<<7 elems) -> GEMM2 rows
// [0,SPLIT) writes (< M<<7 elems into each stripe) never touch live L1 tables, which
// enables the work2 overlap. Row addressing within a table unchanged (rr<<nshift).

__device__ inline void gemm_body(const __hip_bfloat16* __restrict__ A,
                                 const __hip_bfloat16* __restrict__ Bt,   // [NCtot,128]
                                 _Float16* __restrict__ C,
                                 int M, int nshift, int tile_m, int tn0, int tn1, int t,
                                 size_t tblStride, size_t tblOff) {
    __shared__ __hip_bfloat16 Bs[64 * 136];
    int w = t >> 6, lane = t & 63;
    int m16 = lane & 15, quad = lane >> 4;
    int row = tile_m + w * 16 + m16;
    int rowc = row < M ? row : M - 1;

    short8 a[4];
    const short8* ap = (const short8*)(A + (size_t)rowc * 128);
#pragma unroll
    for (int kf = 0; kf < 4; kf++) a[kf] = ap[quad + kf * 4];

    int cmask = (1 << nshift) - 1;

    for (int tn = tn0; tn < tn1; ++tn) {
        int tile_n = tn * 64;
        {
            const uint4* gsrc = (const uint4*)(Bt + (size_t)tile_n * 128);
#pragma unroll
            for (int e = t; e < 64 * 16; e += 256) {
                int n = e >> 4, c = e & 15;
                uint4 val = gsrc[n * 16 + c];
                *(uint4*)(&Bs[n * 136 + c * 8]) = val;
            }
        }
        __syncthreads();

        float4v acc[4];
#pragma unroll
        for (int ct = 0; ct < 4; ct++) {
            acc[ct] = (float4v){0.f, 0.f, 0.f, 0.f};
            const short8* bp = (const short8*)(Bs + (ct * 16 + m16) * 136);
#pragma unroll
            for (int kf = 0; kf < 4; kf++) {
                short8 b = bp[quad + kf * 4];
                acc[ct] = __builtin_amdgcn_mfma_f32_16x16x32_bf16(a[kf], b, acc[ct], 0, 0, 0);
            }
        }
        __syncthreads();   // all LDS reads landed; next iter may overwrite Bs

#pragma unroll
        for (int ct = 0; ct < 4; ct++) {
            int col = tile_n + ct * 16 + m16;
            int tbl = col >> nshift;
            int cc = col & cmask;
            size_t base = (size_t)tbl * tblStride + tblOff;
#pragma unroll
            for (int rg = 0; rg < 4; rg++) {
                int rr = tile_m + w * 16 + quad * 4 + rg;
                if (rr < M) C[base + (((size_t)rr) << nshift) + cc] = (_Float16)acc[ct][rg];
            }
        }
    }
}

__launch_bounds__(256)
__global__ void gemm_kernel(const __hip_bfloat16* __restrict__ A,
                            const __hip_bfloat16* __restrict__ Bt,
                            _Float16* __restrict__ C,
                            int M, int nshift, int tilesPerSplit, int tmBase,
                            size_t tblStride, size_t tblOff) {
    gemm_body(A, Bt, C, M, nshift, (tmBase + blockIdx.x) * 64,
              blockIdx.y * tilesPerSplit, blockIdx.y * tilesPerSplit + tilesPerSplit,
              threadIdx.x, tblStride, tblOff);
}

// ---------------- merged work1: GEMM1 (blocks [0,2346)) + 4-pass scatter ----------------

__launch_bounds__(256)
__global__ void work1_kernel(const __hip_bfloat16* __restrict__ A,
                             const __hip_bfloat16* __restrict__ Bt,
                             _Float16* __restrict__ C,
                             const int* __restrict__ src, const int* __restrict__ dst,
                             int* __restrict__ curs, int* __restrict__ esrc) {
    int wg = blockIdx.x;
    if (wg < 2346) {   // 782 x 3, tilesPerSplit=4, nshift=7, L1 tables in stripe upper halves
        int gx = wg % 782;
        int gy = wg / 782;
        gemm_body(A, Bt, C, NN, 7, gx * 64, gy * 4, gy * 4 + 4, threadIdx.x,
                  (size_t)NN << 8, (size_t)NN << 7);
    } else {
        int wg2 = wg - 2346;          // 0..24575 = 6144 x 4 passes
        int p = wg2 / 6144;
        int i = (wg2 - p * 6144) * 256 + threadIdx.x;
        int d = dst[i];
        if ((unsigned)(d - p * 12500) < 12500u) {
            int r = i >> ESHIFT;
            int pos = atomicAdd(&curs[r * NN + d], 1);
            esrc[pos] = src[i] << 8;
        }
    }
}

// ---------------- fused per-node softmax + aggregation (body) ----------------
// Structure = R6/R8 proven (agg_L2 127 µs, VGPR 48). Table addressing generalized:
// table t at C + t*tstride + toff (bytes); L1: tstride=NN*512, toff=NN*256 (stripe
// upper halves); L2: tstride=NN*512, toff=0. esrc offsets unchanged (src<<8, <<SH).

template <int W2>
__device__ inline void ldrow16(const char* __restrict__ p, half2v* hv) {
    if constexpr (W2 == 2) {   // 4 ch: 8 bytes
        uint2 pk = *(const uint2*)p;
        hv[0] = __builtin_bit_cast(half2v, pk.x);
        hv[1] = __builtin_bit_cast(half2v, pk.y);
    } else {                   // 8 ch: 16 bytes
        uint4 pk = *(const uint4*)p;
        hv[0] = __builtin_bit_cast(half2v, pk.x);
        hv[1] = __builtin_bit_cast(half2v, pk.y);
        hv[2] = __builtin_bit_cast(half2v, pk.z);
        hv[3] = __builtin_bit_cast(half2v, pk.w);
    }
}

template <int W2>
__device__ inline float edot16(const half2v* hv, const half2v* hdv, const half2v* al) {
    const half2v c02 = {(_Float16)0.2f, (_Float16)0.2f};
    float s = 0.f;
#pragma unroll
    for (int j = 0; j < W2; j++) {
        half2v m = hv[j] + hdv[j];                         // v_pk_add_f16
        half2v lr = __builtin_elementwise_max(m, m * c02); // v_pk_mul + v_pk_max
#if USE_FDOT2
        s = __builtin_amdgcn_fdot2(lr, al[j], s, false);   // v_dot2_f32_f16
#else
        half2v tt = lr * al[j];
        s += (float)tt.x + (float)tt.y;
#endif
    }
    return s;
}

template <int CTRL>
__device__ inline float dpp_add(float s) {
    int t = __builtin_amdgcn_update_dpp(0, __float_as_int(s), CTRL, 0xF, 0xF, true);
    return s + __int_as_float(t);
}

__device__ inline float hred8(float s) {
    s = dpp_add<0xB1>(s);
    s = dpp_add<0x4E>(s);
    s = dpp_add<0x141>(s);
    return s;
}

template <int W2, bool L1, int SH>
__device__ inline void agg_body(const char* __restrict__ C, const float* __restrict__ a,
                                const int* __restrict__ offs, const int* __restrict__ deg,
                                const int* __restrict__ esrc,
                                float* __restrict__ outf, __hip_bfloat16* __restrict__ outb,
                                int blockId, int widBase, size_t tstride, size_t toff) {
    const int V = 2 * W2;
    const int NC = 32 * V;
    int wid = widBase + ((blockId * 256 + (int)threadIdx.x) >> 6);
    int lane = threadIdx.x & 63;
    int g = lane >> 5;
    int c = lane & 31;
    int eb = c * V;            // channel offset
    int ebb = eb * 2;          // byte offset within row
    int kb = g << 1;           // interleaved-pair base: half g owns {kb, kb+1, kb+4, kb+5}
    const size_t ROWB = (size_t)NC * 2;

    float2v total[W2];
#pragma unroll
    for (int j = 0; j < W2; j++) total[j] = (float2v){0.f, 0.f};

#pragma unroll 1
    for (int r = 0; r < RR; r++) {
        const char* hsb = C + (size_t)(2 * r) * tstride + toff + ebb;
        const char* hdb = C + (size_t)(2 * r + 1) * tstride + toff + ebb;
        half2v hdv[W2], al[W2];
        float2v acc[W2];
        ldrow16<W2>(hdb + (size_t)wid * ROWB, hdv);
#pragma unroll
        for (int j = 0; j < W2; j++) {
            al[j] = (half2v){(_Float16)(a[r * NC + eb + 2 * j] * LOG2E),
                             (_Float16)(a[r * NC + eb + 2 * j + 1] * LOG2E)};
            acc[j] = (float2v){0.f, 0.f};
        }
        float den = 0.f;
        int e0 = offs[r * NN + wid];
        int dg = deg[r * NN + wid];
        int elast = e0 + ((dg > 0) ? dg : 1) - 1;
        int nfull = dg >> 3;
        int rem = dg & 7;
        int u0 = esrc[min(e0 + kb,     elast)];
        int u1 = esrc[min(e0 + kb + 1, elast)];
        int u2 = esrc[min(e0 + kb + 4, elast)];
        int u3 = esrc[min(e0 + kb + 5, elast)];
        for (int it = 0; it < nfull; ++it) {
            int kn = (it << 3) + 8;
            int n0 = esrc[min(e0 + kn + kb,     elast)];
            int n1 = esrc[min(e0 + kn + kb + 1, elast)];
            int n2 = esrc[min(e0 + kn + kb + 4, elast)];
            int n3 = esrc[min(e0 + kn + kb + 5, elast)];
            half2v hv0[W2], hv1[W2], hv2[W2], hv3[W2];
            ldrow16<W2>(hsb + ((size_t)(unsigned)u0 << SH), hv0);
            ldrow16<W2>(hsb + ((size_t)(unsigned)u1 << SH), hv1);
            ldrow16<W2>(hsb + ((size_t)(unsigned)u2 << SH), hv2);
            ldrow16<W2>(hsb + ((size_t)(unsigned)u3 << SH), hv3);
            float p0 = __builtin_amdgcn_exp2f(hred8(edot16<W2>(hv0, hdv, al)));
            float p1 = __builtin_amdgcn_exp2f(hred8(edot16<W2>(hv1, hdv, al)));
            float p2 = __builtin_amdgcn_exp2f(hred8(edot16<W2>(hv2, hdv, al)));
            float p3 = __builtin_amdgcn_exp2f(hred8(edot16<W2>(hv3, hdv, al)));
            den += (p0 + p1) + (p2 + p3);
#pragma unroll
            for (int j = 0; j < W2; j++) {
                acc[j].x = __builtin_fmaf(p0, (float)hv0[j].x, acc[j].x);
                acc[j].y = __builtin_fmaf(p0, (float)hv0[j].y, acc[j].y);
                acc[j].x = __builtin_fmaf(p1, (float)hv1[j].x, acc[j].x);
                acc[j].y = __builtin_fmaf(p1, (float)hv1[j].y, acc[j].y);
                acc[j].x = __builtin_fmaf(p2, (float)hv2[j].x, acc[j].x);
                acc[j].y = __builtin_fmaf(p2, (float)hv2[j].y, acc[j].y);
                acc[j].x = __builtin_fmaf(p3, (float)hv3[j].x, acc[j].x);
                acc[j].y = __builtin_fmaf(p3, (float)hv3[j].y, acc[j].y);
            }
            u0 = n0; u1 = n1; u2 = n2; u3 = n3;
        }
        if (rem) {
            if (rem <= 4) {
                half2v hv0[W2], hv1[W2];
                ldrow16<W2>(hsb + ((size_t)(unsigned)u0 << SH), hv0);
                ldrow16<W2>(hsb + ((size_t)(unsigned)u1 << SH), hv1);
                float s0 = hred8(edot16<W2>(hv0, hdv, al));
                float s1 = hred8(edot16<W2>(hv1, hdv, al));
                float p0 = (kb     < rem) ? __builtin_amdgcn_exp2f(s0) : 0.f;
                float p1 = (kb + 1 < rem) ? __builtin_amdgcn_exp2f(s1) : 0.f;
                den += p0 + p1;
#pragma unroll
                for (int j = 0; j < W2; j++) {
                    acc[j].x = __builtin_fmaf(p0, (float)hv0[j].x, acc[j].x);
                    acc[j].y = __builtin_fmaf(p0, (float)hv0[j].y, acc[j].y);
                    acc[j].x = __builtin_fmaf(p1, (float)hv1[j].x, acc[j].x);
                    acc[j].y = __builtin_fmaf(p1, (float)hv1[j].y, acc[j].y);
                }
            } else {
                half2v hv0[W2], hv1[W2], hv2[W2], hv3[W2];
                ldrow16<W2>(hsb + ((size_t)(unsigned)u0 << SH), hv0);
                ldrow16<W2>(hsb + ((size_t)(unsigned)u1 << SH), hv1);
                ldrow16<W2>(hsb + ((size_t)(unsigned)u2 << SH), hv2);
                ldrow16<W2>(hsb + ((size_t)(unsigned)u3 << SH), hv3);
                float s0 = hred8(edot16<W2>(hv0, hdv, al));
                float s1 = hred8(edot16<W2>(hv1, hdv, al));
                float s2 = hred8(edot16<W2>(hv2, hdv, al));
                float s3 = hred8(edot16<W2>(hv3, hdv, al));
                float p0 = (kb     < rem) ? __builtin_amdgcn_exp2f(s0) : 0.f;
                float p1 = (kb + 1 < rem) ? __builtin_amdgcn_exp2f(s1) : 0.f;
                float p2 = (kb + 4 < rem) ? __builtin_amdgcn_exp2f(s2) : 0.f;
                float p3 = (kb + 5 < rem) ? __builtin_amdgcn_exp2f(s3) : 0.f;
                den += (p0 + p1) + (p2 + p3);
#pragma unroll
                for (int j = 0; j < W2; j++) {
                    acc[j].x = __builtin_fmaf(p0, (float)hv0[j].x, acc[j].x);
                    acc[j].y = __builtin_fmaf(p0, (float)hv0[j].y, acc[j].y);
                    acc[j].x = __builtin_fmaf(p1, (float)hv1[j].x, acc[j].x);
                    acc[j].y = __builtin_fmaf(p1, (float)hv1[j].y, acc[j].y);
                    acc[j].x = __builtin_fmaf(p2, (float)hv2[j].x, acc[j].x);
                    acc[j].y = __builtin_fmaf(p2, (float)hv2[j].y, acc[j].y);
                    acc[j].x = __builtin_fmaf(p3, (float)hv3[j].x, acc[j].x);
                    acc[j].y = __builtin_fmaf(p3, (float)hv3[j].y, acc[j].y);
                }
            }
        }
        den += __shfl_xor(den, 32);
        float inv = 1.f / (den + 1e-9f);
        float2v iv = (float2v){inv, inv};
#pragma unroll
        for (int j = 0; j < W2; j++) {
            float2v tt = acc[j];
            tt.x += __shfl_xor(tt.x, 32);
            tt.y += __shfl_xor(tt.y, 32);
            total[j] += tt * iv;
        }
    }

    if (g == 0) {
        if constexpr (L1) {
#pragma unroll
            for (int j = 0; j < W2; j++) {
                float v0 = total[j].x, v1 = total[j].y;
                outb[(size_t)wid * NC + eb + 2 * j]     = __float2bfloat16(v0 > 0.f ? v0 : 0.f);
                outb[(size_t)wid * NC + eb + 2 * j + 1] = __float2bfloat16(v1 > 0.f ? v1 : 0.f);
            }
        } else {
#pragma unroll
            for (int j = 0; j < W2; j++) {
                outf[(size_t)wid * NC + eb + 2 * j]     = total[j].x;
                outf[(size_t)wid * NC + eb + 2 * j + 1] = total[j].y;
            }
        }
    }
}

template <int W2, bool L1, int SH>
__launch_bounds__(256)
__global__ void agg_kernel(const char* __restrict__ C, const float* __restrict__ a,
                           const int* __restrict__ offs, const int* __restrict__ deg,
                           const int* __restrict__ esrc,
                           float* __restrict__ outf, __hip_bfloat16* __restrict__ outb,
                           int widBase, size_t tstride, size_t toff) {
    agg_body<W2, L1, SH>(C, a, offs, deg, esrc, outf, outb, blockIdx.x, widBase, tstride, toff);
}

// ---------------- merged work2: GEMM2 rows [0,SPLIT) || agg_L1 nodes [SPLIT,NN) ----------------
// GEMM2-h0 reads hb rows [0,SPLIT) (done by agg_L1-h0) and writes stripe lower halves
// (disjoint from L1 tables). agg_L1-h1 reads L1 tables (stripe upper halves) and writes
// hb rows [SPLIT,NN). GEMM blocks first (long, MFMA-bound) -> overlap with gather waves.

__launch_bounds__(256)
__global__ void work2_kernel(const __hip_bfloat16* __restrict__ hb,
                             const __hip_bfloat16* __restrict__ T2,
                             _Float16* __restrict__ Cb,
                             const char* __restrict__ C1, const float* __restrict__ a1,
                             const int* __restrict__ offs, const int* __restrict__ deg,
                             const int* __restrict__ esrc,
                             __hip_bfloat16* __restrict__ hbout) {
    int wg = blockIdx.x;
    if (wg < 1560) {   // GEMM2-h0: 390 tiles x 4 y-splits, 6 n-tiles each
        int gx = wg % 390;
        int gy = wg / 390;
        gemm_body(hb, T2, Cb, NN, 8, gx * 64, gy * 6, gy * 6 + 6, threadIdx.x,
                  (size_t)NN << 8, 0);
    } else {           // agg_L1-h1: 6260 blocks, nodes [24960, 50000)
        agg_body<2, true, 0>(C1, a1, offs, deg, esrc, nullptr, hbout,
                             wg - 1560, SPLIT, (size_t)NN * 512, (size_t)NN * 256);
    }
}

// ---------------- launch ----------------

extern "C" void kernel_launch(void* const* d_in, const int* in_sizes, int n_in,
                              void* d_out, int out_size, void* d_ws, size_t ws_size,
                              hipStream_t stream) {
    const float* x   = (const float*)d_in[0];
    const int*   src = (const int*)d_in[1];
    const int*   dst = (const int*)d_in[2];
    const float* W1s = (const float*)d_in[3];
    const float* W1d = (const float*)d_in[4];
    const float* a1  = (const float*)d_in[5];
    const float* W2s = (const float*)d_in[6];
    const float* W2d = (const float*)d_in[7];
    const float* a2  = (const float*)d_in[8];

    char* ws = (char*)d_ws;
    size_t off = 0;
    auto alloc = [&](size_t bytes) -> void* {
        void* p = ws + off;
        off += (bytes + 255) & ~(size_t)255;
        return p;
    };
    __hip_bfloat16* xb = (__hip_bfloat16*)alloc((size_t)NN * 128 * 2);
    __hip_bfloat16* hb = (__hip_bfloat16*)alloc((size_t)NN * 128 * 2);
    _Float16*       Cb = (_Float16*)alloc((size_t)NN * 1536 * 2);  // 6 stripes of M*256 f16
    __hip_bfloat16* T1 = (__hip_bfloat16*)alloc((size_t)768 * 128 * 2);
    __hip_bfloat16* T2 = (__hip_bfloat16*)alloc((size_t)1536 * 128 * 2);
    int* deg  = (int*)alloc((size_t)TN * 4);
    int* offs = (int*)alloc((size_t)TN * 4);
    int* curs = (int*)alloc((size_t)TN * 4);
    int* esrc = (int*)alloc((size_t)RR * EE * 4);
    int* part = (int*)alloc(4096);

    float* outp = (float*)d_out;

    // 1) zero histograms
    hipMemsetAsync(deg, 0, (size_t)TN * 4, stream);

    // 2) merged prep: conv + 4 transposes + hist
    prep_kernel<<<13546, 256, 0, stream>>>(x, (short4v*)xb, W1s, W1d, W2s, W2d,
                                           T1, T2, dst, deg);

    // 3-5) CSR scan
    scan1_kernel<<<NCHUNK, 256, 0, stream>>>(deg, part);
    scan2_kernel<<<1, 1, 0, stream>>>(part);
    scan3_kernel<<<NCHUNK, 256, 0, stream>>>(deg, part, offs, curs);

    // 6) work1: GEMM1 (L1 tables -> stripe upper halves) || scatter
    work1_kernel<<<2346 + 24576, 256, 0, stream>>>(xb, T1, Cb, src, dst, curs, esrc);

    // 7) agg_L1 h0: nodes [0, 24960) -> hb rows [0, 24960)
    agg_kernel<2, true, 0><<<6240, 256, 0, stream>>>((const char*)Cb, a1, offs, deg, esrc,
                                                     nullptr, hb, 0,
                                                     (size_t)NN * 512, (size_t)NN * 256);

    // 8) work2: GEMM2 rows [0,24960) || agg_L1 nodes [24960, 50000)
    work2_kernel<<<1560 + 6260, 256, 0, stream>>>(hb, T2, Cb, (const char*)Cb, a1,
                                                  offs, deg, esrc, hb);

    // 9) GEMM2 h1: tiles [390, 782) -> rows [24960, 50000)
    gemm_kernel<<<dim3(392, 4), 256, 0, stream>>>(hb, T2, Cb, NN, 8, 6, 390,
                                                  (size_t)NN << 8, 0);

    // 10) agg_L2 -> f32 d_out
    agg_kernel<4, false, 1><<<12500, 256, 0, stream>>>((const char*)Cb, a2, offs, deg, esrc,
                                                       outp, nullptr, 0,
                                                       (size_t)NN * 512, 0);
}

// Round 10
// 516.350 us; speedup vs baseline: 1.0249x; 1.0249x over previous
//
#include <hip/hip_runtime.h>
#include <hip/hip_bf16.h>

#define NN 50000
#define HH 4
#define RR 3
#define EE 524288      // 2^19
#define ESHIFT 19
#define TN (RR*NN)     // 150000
#define NCHUNK ((TN + 1023)/1024)  // 147
#define LOG2E 1.4426950408889634f

typedef __attribute__((ext_vector_type(8))) short short8;
typedef __attribute__((ext_vector_type(4))) short short4v;
typedef __attribute__((ext_vector_type(4))) float float4v;
typedef __attribute__((ext_vector_type(2))) float float2v;
typedef __attribute__((ext_vector_type(2))) _Float16 half2v;

#if defined(__has_builtin)
#if __has_builtin(__builtin_amdgcn_fdot2)
#define USE_FDOT2 1
#else
#define USE_FDOT2 0
#endif
#else
#define USE_FDOT2 0
#endif

// ---------------- merged prep: conv + 4 weight transposes + hist ----------------

__device__ inline void tw_body(const float* __restrict__ W, __hip_bfloat16* __restrict__ T,
                               int ncs, int colOff, int i) {
    int r = i >> (7 + ncs);
    int rem = i & ((128 << ncs) - 1);
    int k = rem >> ncs;
    int n = rem & ((1 << ncs) - 1);
    T[(size_t)((r << (1 + ncs)) + colOff + n) * 128 + k] = __float2bfloat16(W[i]);
}

__launch_bounds__(256)
__global__ void prep_kernel(const float* __restrict__ x, short4v* __restrict__ xb,
                            const float* __restrict__ W1s, const float* __restrict__ W1d,
                            const float* __restrict__ W2s, const float* __restrict__ W2d,
                            __hip_bfloat16* __restrict__ T1, __hip_bfloat16* __restrict__ T2,
                            const int* __restrict__ dst, int* __restrict__ deg) {
    int wg = blockIdx.x, t = threadIdx.x;
    if (wg < 6250) {                       // conv: NN*128/4 = 1.6M elems, exact
        int i = wg * 256 + t;
        float4v v = ((const float4v*)x)[i];
        short4v o;
        o.x = (short)__bfloat16_as_ushort(__float2bfloat16(v.x));
        o.y = (short)__bfloat16_as_ushort(__float2bfloat16(v.y));
        o.z = (short)__bfloat16_as_ushort(__float2bfloat16(v.z));
        o.w = (short)__bfloat16_as_ushort(__float2bfloat16(v.w));
        xb[i] = o;
    } else if (wg < 6442) {                // W1s: 3*128*128 = 192 blocks exact
        tw_body(W1s, T1, 7, 0, (wg - 6250) * 256 + t);
    } else if (wg < 6634) {                // W1d
        tw_body(W1d, T1, 7, 128, (wg - 6442) * 256 + t);
    } else if (wg < 7018) {                // W2s: 3*128*256 = 384 blocks exact
        tw_body(W2s, T2, 8, 0, (wg - 6634) * 256 + t);
    } else if (wg < 7402) {                // W2d
        tw_body(W2d, T2, 8, 256, (wg - 7018) * 256 + t);
    } else {                               // hist: 3E/256 = 6144 blocks exact
        int i = (wg - 7402) * 256 + t;
        int r = i >> ESHIFT;
        atomicAdd(&deg[r * NN + dst[i]], 1);
    }
}

// ---------------- CSR scan: proven 3-kernel chain ----------------

__global__ void scan1_kernel(const int* __restrict__ deg, int* __restrict__ part) {
    __shared__ int s[256];
    int t = threadIdx.x;
    int base = blockIdx.x * 1024 + t * 4;
    int sum = 0;
#pragma unroll
    for (int j = 0; j < 4; j++) {
        int idx = base + j;
        sum += (idx < TN) ? deg[idx] : 0;
    }
    s[t] = sum;
    __syncthreads();
    for (int off = 128; off > 0; off >>= 1) {
        if (t < off) s[t] += s[t + off];
        __syncthreads();
    }
    if (t == 0) part[blockIdx.x] = s[0];
}

__global__ void scan2_kernel(int* part) {
    int run = 0;
    for (int i = 0; i < NCHUNK; i++) {
        int v = part[i];
        part[i] = run;
        run += v;
    }
}

__global__ void scan3_kernel(const int* __restrict__ deg, const int* __restrict__ part,
                             int* __restrict__ offs, int* __restrict__ curs) {
    __shared__ int s[256];
    int t = threadIdx.x;
    int base = blockIdx.x * 1024 + t * 4;
    int v[4];
    int tsum = 0;
#pragma unroll
    for (int j = 0; j < 4; j++) {
        int idx = base + j;
        v[j] = (idx < TN) ? deg[idx] : 0;
        tsum += v[j];
    }
    s[t] = tsum;
    __syncthreads();
    for (int off = 1; off < 256; off <<= 1) {
        int x = (t >= off) ? s[t - off] : 0;
        __syncthreads();
        s[t] += x;
        __syncthreads();
    }
    int excl = s[t] - tsum + part[blockIdx.x];
    int run = excl;
#pragma unroll
    for (int j = 0; j < 4; j++) {
        int idx = base + j;
        if (idx < TN) {
            offs[idx] = run;
            curs[idx] = run;
            run += v[j];
        }
    }
}

// ---------------- GEMM body (R8 layout: table t at tbl*M<<nshift) ----------------

__device__ inline void gemm_body(const __hip_bfloat16* __restrict__ A,
                                 const __hip_bfloat16* __restrict__ Bt,   // [NCtot,128]
                                 _Float16* __restrict__ C,
                                 int M, int nshift, int tile_m, int tn0, int tn1, int t) {
    __shared__ __hip_bfloat16 Bs[64 * 136];
    int w = t >> 6, lane = t & 63;
    int m16 = lane & 15, quad = lane >> 4;
    int row = tile_m + w * 16 + m16;
    int rowc = row < M ? row : M - 1;

    short8 a[4];
    const short8* ap = (const short8*)(A + (size_t)rowc * 128);
#pragma unroll
    for (int kf = 0; kf < 4; kf++) a[kf] = ap[quad + kf * 4];

    int cmask = (1 << nshift) - 1;

    for (int tn = tn0; tn < tn1; ++tn) {
        int tile_n = tn * 64;
        {
            const uint4* gsrc = (const uint4*)(Bt + (size_t)tile_n * 128);
#pragma unroll
            for (int e = t; e < 64 * 16; e += 256) {
                int n = e >> 4, c = e & 15;
                uint4 val = gsrc[n * 16 + c];
                *(uint4*)(&Bs[n * 136 + c * 8]) = val;
            }
        }
        __syncthreads();

        float4v acc[4];
#pragma unroll
        for (int ct = 0; ct < 4; ct++) {
            acc[ct] = (float4v){0.f, 0.f, 0.f, 0.f};
            const short8* bp = (const short8*)(Bs + (ct * 16 + m16) * 136);
#pragma unroll
            for (int kf = 0; kf < 4; kf++) {
                short8 b = bp[quad + kf * 4];
                acc[ct] = __builtin_amdgcn_mfma_f32_16x16x32_bf16(a[kf], b, acc[ct], 0, 0, 0);
            }
        }
        __syncthreads();   // all LDS reads landed; next iter may overwrite Bs

#pragma unroll
        for (int ct = 0; ct < 4; ct++) {
            int col = tile_n + ct * 16 + m16;
            int tbl = col >> nshift;
            int cc = col & cmask;
            size_t base = ((size_t)tbl * M) << nshift;
#pragma unroll
            for (int rg = 0; rg < 4; rg++) {
                int rr = tile_m + w * 16 + quad * 4 + rg;
                if (rr < M) C[base + (((size_t)rr) << nshift) + cc] = (_Float16)acc[ct][rg];
            }
        }
    }
}

__launch_bounds__(256)
__global__ void gemm_kernel(const __hip_bfloat16* __restrict__ A,
                            const __hip_bfloat16* __restrict__ Bt,
                            _Float16* __restrict__ C,
                            int M, int nshift, int tilesPerSplit) {
    gemm_body(A, Bt, C, M, nshift, blockIdx.x * 64,
              blockIdx.y * tilesPerSplit, blockIdx.y * tilesPerSplit + tilesPerSplit,
              threadIdx.x);
}

// ---------------- merged work1: GEMM1 (blocks [0,2346)) + 4-pass scatter ----------------

__launch_bounds__(256)
__global__ void work1_kernel(const __hip_bfloat16* __restrict__ A,
                             const __hip_bfloat16* __restrict__ Bt,
                             _Float16* __restrict__ C,
                             const int* __restrict__ src, const int* __restrict__ dst,
                             int* __restrict__ curs, int* __restrict__ esrc) {
    int wg = blockIdx.x;
    if (wg < 2346) {   // 782 x 3, tilesPerSplit=4, nshift=7
        int gx = wg % 782;
        int gy = wg / 782;
        gemm_body(A, Bt, C, NN, 7, gx * 64, gy * 4, gy * 4 + 4, threadIdx.x);
    } else {
        int wg2 = wg - 2346;          // 0..24575 = 6144 x 4 passes
        int p = wg2 / 6144;
        int i = (wg2 - p * 6144) * 256 + threadIdx.x;
        int d = dst[i];
        if ((unsigned)(d - p * 12500) < 12500u) {
            int r = i >> ESHIFT;
            int pos = atomicAdd(&curs[r * NN + d], 1);
            esrc[pos] = src[i] << 8;
        }
    }
}

// ---------------- fused per-node softmax + aggregation ----------------
// R10 restructure: ONE WAVE PER (node, relation). 192-thread block = 1 node x 3
// relation-waves. Per-wave serial chain drops 3x (single relation's dependent-load
// chain: offs/deg -> esrc -> rows) and resident wave count triples -- attacks the
// measured latency-bound signature (VALU 67%, HBM 47%, occ 48%: nothing saturated).
// R4's within-wave version of this died on VGPR pressure; cross-wave split shrinks
// per-wave registers instead. Per-relation softmax is independent (den is
// per-relation), so waves 1,2 deposit normalized partials in LDS (2 KB), wave 0
// sums + applies relu/cast (L1) or writes f32 (L2).
// Inner loop byte-identical to R8's proven form (interleaved slot pairs + short
// tail, DPP-only 8-lane reduce, f16 tables, packed math + fdot2, f32 accumulate).

template <int W2>
__device__ inline void ldrow16(const char* __restrict__ p, half2v* hv) {
    if constexpr (W2 == 2) {   // 4 ch: 8 bytes
        uint2 pk = *(const uint2*)p;
        hv[0] = __builtin_bit_cast(half2v, pk.x);
        hv[1] = __builtin_bit_cast(half2v, pk.y);
    } else {                   // 8 ch: 16 bytes
        uint4 pk = *(const uint4*)p;
        hv[0] = __builtin_bit_cast(half2v, pk.x);
        hv[1] = __builtin_bit_cast(half2v, pk.y);
        hv[2] = __builtin_bit_cast(half2v, pk.z);
        hv[3] = __builtin_bit_cast(half2v, pk.w);
    }
}

template <int W2>
__device__ inline float edot16(const half2v* hv, const half2v* hdv, const half2v* al) {
    const half2v c02 = {(_Float16)0.2f, (_Float16)0.2f};
    float s = 0.f;
#pragma unroll
    for (int j = 0; j < W2; j++) {
        half2v m = hv[j] + hdv[j];                         // v_pk_add_f16
        half2v lr = __builtin_elementwise_max(m, m * c02); // v_pk_mul + v_pk_max
#if USE_FDOT2
        s = __builtin_amdgcn_fdot2(lr, al[j], s, false);   // v_dot2_f32_f16
#else
        half2v tt = lr * al[j];
        s += (float)tt.x + (float)tt.y;
#endif
    }
    return s;
}

template <int CTRL>
__device__ inline float dpp_add(float s) {
    int t = __builtin_amdgcn_update_dpp(0, __float_as_int(s), CTRL, 0xF, 0xF, true);
    return s + __int_as_float(t);
}

__device__ inline float hred8(float s) {
    s = dpp_add<0xB1>(s);
    s = dpp_add<0x4E>(s);
    s = dpp_add<0x141>(s);
    return s;
}

template <int W2, bool L1, int SH>
__launch_bounds__(192)
__global__ void agg_kernel(const char* __restrict__ C,               // f16 tables, byte-addressed
                           const float* __restrict__ a,              // [R][NC]
                           const int* __restrict__ offs, const int* __restrict__ deg,
                           const int* __restrict__ esrc,             // byte offsets (src<<8)
                           float* __restrict__ outf, __hip_bfloat16* __restrict__ outb) {
    const int V = 2 * W2;
    const int NC = 32 * V;
    const int ROWB = NC * 2;                          // row bytes
    int wid = blockIdx.x;                             // node id, < 50000 exact
    int r = threadIdx.x >> 6;                         // relation 0..2 (wave id)
    int lane = threadIdx.x & 63;
    int g = lane >> 5;
    int c = lane & 31;
    int eb = c * V;            // channel offset
    int ebb = eb * 2;          // byte offset within row
    int kb = g << 1;           // interleaved-pair base: half g owns {kb, kb+1, kb+4, kb+5}

    __shared__ float red[2][32][2 * W2];              // waves 1,2 deposit partials

    const char* hsb = C + (size_t)(2 * r) * NN * ROWB + ebb;
    const char* hdb = C + (size_t)(2 * r + 1) * NN * ROWB + ebb;
    half2v hdv[W2], al[W2];
    float2v acc[W2];
    ldrow16<W2>(hdb + (size_t)wid * ROWB, hdv);
#pragma unroll
    for (int j = 0; j < W2; j++) {
        al[j] = (half2v){(_Float16)(a[r * NC + eb + 2 * j] * LOG2E),
                         (_Float16)(a[r * NC + eb + 2 * j + 1] * LOG2E)};
        acc[j] = (float2v){0.f, 0.f};
    }
    float den = 0.f;
    int e0 = offs[r * NN + wid];
    int dg = deg[r * NN + wid];
    int elast = e0 + ((dg > 0) ? dg : 1) - 1;
    int nfull = dg >> 3;
    int rem = dg & 7;
    int u0 = esrc[min(e0 + kb,     elast)];
    int u1 = esrc[min(e0 + kb + 1, elast)];
    int u2 = esrc[min(e0 + kb + 4, elast)];
    int u3 = esrc[min(e0 + kb + 5, elast)];
    for (int it = 0; it < nfull; ++it) {
        int kn = (it << 3) + 8;
        int n0 = esrc[min(e0 + kn + kb,     elast)];
        int n1 = esrc[min(e0 + kn + kb + 1, elast)];
        int n2 = esrc[min(e0 + kn + kb + 4, elast)];
        int n3 = esrc[min(e0 + kn + kb + 5, elast)];
        half2v hv0[W2], hv1[W2], hv2[W2], hv3[W2];
        ldrow16<W2>(hsb + ((size_t)(unsigned)u0 << SH), hv0);
        ldrow16<W2>(hsb + ((size_t)(unsigned)u1 << SH), hv1);
        ldrow16<W2>(hsb + ((size_t)(unsigned)u2 << SH), hv2);
        ldrow16<W2>(hsb + ((size_t)(unsigned)u3 << SH), hv3);
        float p0 = __builtin_amdgcn_exp2f(hred8(edot16<W2>(hv0, hdv, al)));
        float p1 = __builtin_amdgcn_exp2f(hred8(edot16<W2>(hv1, hdv, al)));
        float p2 = __builtin_amdgcn_exp2f(hred8(edot16<W2>(hv2, hdv, al)));
        float p3 = __builtin_amdgcn_exp2f(hred8(edot16<W2>(hv3, hdv, al)));
        den += (p0 + p1) + (p2 + p3);
#pragma unroll
        for (int j = 0; j < W2; j++) {
            acc[j].x = __builtin_fmaf(p0, (float)hv0[j].x, acc[j].x);
            acc[j].y = __builtin_fmaf(p0, (float)hv0[j].y, acc[j].y);
            acc[j].x = __builtin_fmaf(p1, (float)hv1[j].x, acc[j].x);
            acc[j].y = __builtin_fmaf(p1, (float)hv1[j].y, acc[j].y);
            acc[j].x = __builtin_fmaf(p2, (float)hv2[j].x, acc[j].x);
            acc[j].y = __builtin_fmaf(p2, (float)hv2[j].y, acc[j].y);
            acc[j].x = __builtin_fmaf(p3, (float)hv3[j].x, acc[j].x);
            acc[j].y = __builtin_fmaf(p3, (float)hv3[j].y, acc[j].y);
        }
        u0 = n0; u1 = n1; u2 = n2; u3 = n3;
    }
    if (rem) {
        if (rem <= 4) {
            half2v hv0[W2], hv1[W2];
            ldrow16<W2>(hsb + ((size_t)(unsigned)u0 << SH), hv0);
            ldrow16<W2>(hsb + ((size_t)(unsigned)u1 << SH), hv1);
            float s0 = hred8(edot16<W2>(hv0, hdv, al));
            float s1 = hred8(edot16<W2>(hv1, hdv, al));
            float p0 = (kb     < rem) ? __builtin_amdgcn_exp2f(s0) : 0.f;
            float p1 = (kb + 1 < rem) ? __builtin_amdgcn_exp2f(s1) : 0.f;
            den += p0 + p1;
#pragma unroll
            for (int j = 0; j < W2; j++) {
                acc[j].x = __builtin_fmaf(p0, (float)hv0[j].x, acc[j].x);
                acc[j].y = __builtin_fmaf(p0, (float)hv0[j].y, acc[j].y);
                acc[j].x = __builtin_fmaf(p1, (float)hv1[j].x, acc[j].x);
                acc[j].y = __builtin_fmaf(p1, (float)hv1[j].y, acc[j].y);
            }
        } else {
            half2v hv0[W2], hv1[W2], hv2[W2], hv3[W2];
            ldrow16<W2>(hsb + ((size_t)(unsigned)u0 << SH), hv0);
            ldrow16<W2>(hsb + ((size_t)(unsigned)u1 << SH), hv1);
            ldrow16<W2>(hsb + ((size_t)(unsigned)u2 << SH), hv2);
            ldrow16<W2>(hsb + ((size_t)(unsigned)u3 << SH), hv3);
            float s0 = hred8(edot16<W2>(hv0, hdv, al));
            float s1 = hred8(edot16<W2>(hv1, hdv, al));
            float s2 = hred8(edot16<W2>(hv2, hdv, al));
            float s3 = hred8(edot16<W2>(hv3, hdv, al));
            float p0 = (kb     < rem) ? __builtin_amdgcn_exp2f(s0) : 0.f;
            float p1 = (kb + 1 < rem) ? __builtin_amdgcn_exp2f(s1) : 0.f;
            float p2 = (kb + 4 < rem) ? __builtin_amdgcn_exp2f(s2) : 0.f;
            float p3 = (kb + 5 < rem) ? __builtin_amdgcn_exp2f(s3) : 0.f;
            den += (p0 + p1) + (p2 + p3);
#pragma unroll
            for (int j = 0; j < W2; j++) {
                acc[j].x = __builtin_fmaf(p0, (float)hv0[j].x, acc[j].x);
                acc[j].y = __builtin_fmaf(p0, (float)hv0[j].y, acc[j].y);
                acc[j].x = __builtin_fmaf(p1, (float)hv1[j].x, acc[j].x);
                acc[j].y = __builtin_fmaf(p1, (float)hv1[j].y, acc[j].y);
                acc[j].x = __builtin_fmaf(p2, (float)hv2[j].x, acc[j].x);
                acc[j].y = __builtin_fmaf(p2, (float)hv2[j].y, acc[j].y);
                acc[j].x = __builtin_fmaf(p3, (float)hv3[j].x, acc[j].x);
                acc[j].y = __builtin_fmaf(p3, (float)hv3[j].y, acc[j].y);
            }
        }
    }
    // combine the two edge-halves within this relation's wave, normalize
    den += __shfl_xor(den, 32);
    float inv = 1.f / (den + 1e-9f);
    float2v iv = (float2v){inv, inv};
    float2v part[W2];
#pragma unroll
    for (int j = 0; j < W2; j++) {
        float2v tt = acc[j];
        tt.x += __shfl_xor(tt.x, 32);
        tt.y += __shfl_xor(tt.y, 32);
        part[j] = tt * iv;
    }

    // cross-relation combine via LDS: waves 1,2 deposit; wave 0 sums + writes
    if (r > 0 && g == 0) {
#pragma unroll
        for (int j = 0; j < W2; j++) {
            red[r - 1][c][2 * j]     = part[j].x;
            red[r - 1][c][2 * j + 1] = part[j].y;
        }
    }
    __syncthreads();
    if (r == 0 && g == 0) {
#pragma unroll
        for (int j = 0; j < W2; j++) {
            float v0 = part[j].x + red[0][c][2 * j]     + red[1][c][2 * j];
            float v1 = part[j].y + red[0][c][2 * j + 1] + red[1][c][2 * j + 1];
            if constexpr (L1) {
                outb[(size_t)wid * NC + eb + 2 * j]     = __float2bfloat16(v0 > 0.f ? v0 : 0.f);
                outb[(size_t)wid * NC + eb + 2 * j + 1] = __float2bfloat16(v1 > 0.f ? v1 : 0.f);
            } else {
                outf[(size_t)wid * NC + eb + 2 * j]     = v0;
                outf[(size_t)wid * NC + eb + 2 * j + 1] = v1;
            }
        }
    }
}

// ---------------- launch ----------------

extern "C" void kernel_launch(void* const* d_in, const int* in_sizes, int n_in,
                              void* d_out, int out_size, void* d_ws, size_t ws_size,
                              hipStream_t stream) {
    const float* x   = (const float*)d_in[0];
    const int*   src = (const int*)d_in[1];
    const int*   dst = (const int*)d_in[2];
    const float* W1s = (const float*)d_in[3];
    const float* W1d = (const float*)d_in[4];
    const float* a1  = (const float*)d_in[5];
    const float* W2s = (const float*)d_in[6];
    const float* W2d = (const float*)d_in[7];
    const float* a2  = (const float*)d_in[8];

    char* ws = (char*)d_ws;
    size_t off = 0;
    auto alloc = [&](size_t bytes) -> void* {
        void* p = ws + off;
        off += (bytes + 255) & ~(size_t)255;
        return p;
    };
    __hip_bfloat16* xb = (__hip_bfloat16*)alloc((size_t)NN * 128 * 2);
    __hip_bfloat16* hb = (__hip_bfloat16*)alloc((size_t)NN * 128 * 2);
    _Float16*       Cb = (_Float16*)alloc((size_t)NN * 1536 * 2);  // 6 tables
    __hip_bfloat16* T1 = (__hip_bfloat16*)alloc((size_t)768 * 128 * 2);
    __hip_bfloat16* T2 = (__hip_bfloat16*)alloc((size_t)1536 * 128 * 2);
    int* deg  = (int*)alloc((size_t)TN * 4);
    int* offs = (int*)alloc((size_t)TN * 4);
    int* curs = (int*)alloc((size_t)TN * 4);
    int* esrc = (int*)alloc((size_t)RR * EE * 4);
    int* part = (int*)alloc(4096);

    float* outp = (float*)d_out;

    // 1) zero histograms
    hipMemsetAsync(deg, 0, (size_t)TN * 4, stream);

    // 2) merged prep: conv + 4 transposes + hist
    prep_kernel<<<13546, 256, 0, stream>>>(x, (short4v*)xb, W1s, W1d, W2s, W2d,
                                           T1, T2, dst, deg);

    // 3-5) CSR scan
    scan1_kernel<<<NCHUNK, 256, 0, stream>>>(deg, part);
    scan2_kernel<<<1, 1, 0, stream>>>(part);
    scan3_kernel<<<NCHUNK, 256, 0, stream>>>(deg, part, offs, curs);

    // 6) work1: GEMM1 || scatter
    work1_kernel<<<2346 + 24576, 256, 0, stream>>>(xb, T1, Cb, src, dst, curs, esrc);

    // 7) agg layer 1: one block per node, 3 relation-waves (fuses relu + bf16 -> hb)
    agg_kernel<2, true, 0><<<NN, 192, 0, stream>>>((const char*)Cb, a1, offs, deg, esrc,
                                                   nullptr, hb);

    // 8) GEMM2 [N,128]x[128,1536] -> 6 compact [N,256] f16 tables (4-way N split)
    gemm_kernel<<<dim3(782, 4), 256, 0, stream>>>(hb, T2, Cb, NN, 8, 6);

    // 9) agg layer 2: one block per node, 3 relation-waves -> f32 d_out
    agg_kernel<4, false, 1><<<NN, 192, 0, stream>>>((const char*)Cb, a2, offs, deg, esrc,
                                                    outp, nullptr);
}

// Round 11
// 508.976 us; speedup vs baseline: 1.0397x; 1.0145x over previous
//
#include <hip/hip_runtime.h>
#include <hip/hip_bf16.h>

#define NN 50000
#define HH 4
#define RR 3
#define EE 524288      // 2^19
#define ESHIFT 19
#define TN (RR*NN)     // 150000
#define NCHUNK ((TN + 1023)/1024)  // 147
#define LOG2E 1.4426950408889634f

typedef __attribute__((ext_vector_type(8))) short short8;
typedef __attribute__((ext_vector_type(4))) short short4v;
typedef __attribute__((ext_vector_type(4))) float float4v;
typedef __attribute__((ext_vector_type(2))) float float2v;
typedef __attribute__((ext_vector_type(2))) _Float16 half2v;

#if defined(__has_builtin)
#if __has_builtin(__builtin_amdgcn_fdot2)
#define USE_FDOT2 1
#else
#define USE_FDOT2 0
#endif
#else
#define USE_FDOT2 0
#endif

// ---------------- merged prep: conv + 4 weight transposes + hist ----------------

__device__ inline void tw_body(const float* __restrict__ W, __hip_bfloat16* __restrict__ T,
                               int ncs, int colOff, int i) {
    int r = i >> (7 + ncs);
    int rem = i & ((128 << ncs) - 1);
    int k = rem >> ncs;
    int n = rem & ((1 << ncs) - 1);
    T[(size_t)((r << (1 + ncs)) + colOff + n) * 128 + k] = __float2bfloat16(W[i]);
}

__launch_bounds__(256)
__global__ void prep_kernel(const float* __restrict__ x, short4v* __restrict__ xb,
                            const float* __restrict__ W1s, const float* __restrict__ W1d,
                            const float* __restrict__ W2s, const float* __restrict__ W2d,
                            __hip_bfloat16* __restrict__ T1, __hip_bfloat16* __restrict__ T2,
                            const int* __restrict__ dst, int* __restrict__ deg) {
    int wg = blockIdx.x, t = threadIdx.x;
    if (wg < 6250) {                       // conv: NN*128/4 = 1.6M elems, exact
        int i = wg * 256 + t;
        float4v v = ((const float4v*)x)[i];
        short4v o;
        o.x = (short)__bfloat16_as_ushort(__float2bfloat16(v.x));
        o.y = (short)__bfloat16_as_ushort(__float2bfloat16(v.y));
        o.z = (short)__bfloat16_as_ushort(__float2bfloat16(v.z));
        o.w = (short)__bfloat16_as_ushort(__float2bfloat16(v.w));
        xb[i] = o;
    } else if (wg < 6442) {                // W1s: 3*128*128 = 192 blocks exact
        tw_body(W1s, T1, 7, 0, (wg - 6250) * 256 + t);
    } else if (wg < 6634) {                // W1d
        tw_body(W1d, T1, 7, 128, (wg - 6442) * 256 + t);
    } else if (wg < 7018) {                // W2s: 3*128*256 = 384 blocks exact
        tw_body(W2s, T2, 8, 0, (wg - 6634) * 256 + t);
    } else if (wg < 7402) {                // W2d
        tw_body(W2d, T2, 8, 256, (wg - 7018) * 256 + t);
    } else {                               // hist: 3E/256 = 6144 blocks exact
        int i = (wg - 7402) * 256 + t;
        int r = i >> ESHIFT;
        atomicAdd(&deg[r * NN + dst[i]], 1);
    }
}

// ---------------- CSR scan: proven 3-kernel chain ----------------

__global__ void scan1_kernel(const int* __restrict__ deg, int* __restrict__ part) {
    __shared__ int s[256];
    int t = threadIdx.x;
    int base = blockIdx.x * 1024 + t * 4;
    int sum = 0;
#pragma unroll
    for (int j = 0; j < 4; j++) {
        int idx = base + j;
        sum += (idx < TN) ? deg[idx] : 0;
    }
    s[t] = sum;
    __syncthreads();
    for (int off = 128; off > 0; off >>= 1) {
        if (t < off) s[t] += s[t + off];
        __syncthreads();
    }
    if (t == 0) part[blockIdx.x] = s[0];
}

__global__ void scan2_kernel(int* part) {
    int run = 0;
    for (int i = 0; i < NCHUNK; i++) {
        int v = part[i];
        part[i] = run;
        run += v;
    }
}

__global__ void scan3_kernel(const int* __restrict__ deg, const int* __restrict__ part,
                             int* __restrict__ offs, int* __restrict__ curs) {
    __shared__ int s[256];
    int t = threadIdx.x;
    int base = blockIdx.x * 1024 + t * 4;
    int v[4];
    int tsum = 0;
#pragma unroll
    for (int j = 0; j < 4; j++) {
        int idx = base + j;
        v[j] = (idx < TN) ? deg[idx] : 0;
        tsum += v[j];
    }
    s[t] = tsum;
    __syncthreads();
    for (int off = 1; off < 256; off <<= 1) {
        int x = (t >= off) ? s[t - off] : 0;
        __syncthreads();
        s[t] += x;
        __syncthreads();
    }
    int excl = s[t] - tsum + part[blockIdx.x];
    int run = excl;
#pragma unroll
    for (int j = 0; j < 4; j++) {
        int idx = base + j;
        if (idx < TN) {
            offs[idx] = run;
            curs[idx] = run;
            run += v[j];
        }
    }
}

// ---------------- GEMM body (R8 layout: table t at tbl*M<<nshift) ----------------

__device__ inline void gemm_body(const __hip_bfloat16* __restrict__ A,
                                 const __hip_bfloat16* __restrict__ Bt,   // [NCtot,128]
                                 _Float16* __restrict__ C,
                                 int M, int nshift, int tile_m, int tn0, int tn1, int t) {
    __shared__ __hip_bfloat16 Bs[64 * 136];
    int w = t >> 6, lane = t & 63;
    int m16 = lane & 15, quad = lane >> 4;
    int row = tile_m + w * 16 + m16;
    int rowc = row < M ? row : M - 1;

    short8 a[4];
    const short8* ap = (const short8*)(A + (size_t)rowc * 128);
#pragma unroll
    for (int kf = 0; kf < 4; kf++) a[kf] = ap[quad + kf * 4];

    int cmask = (1 << nshift) - 1;

    for (int tn = tn0; tn < tn1; ++tn) {
        int tile_n = tn * 64;
        {
            const uint4* gsrc = (const uint4*)(Bt + (size_t)tile_n * 128);
#pragma unroll
            for (int e = t; e < 64 * 16; e += 256) {
                int n = e >> 4, c = e & 15;
                uint4 val = gsrc[n * 16 + c];
                *(uint4*)(&Bs[n * 136 + c * 8]) = val;
            }
        }
        __syncthreads();

        float4v acc[4];
#pragma unroll
        for (int ct = 0; ct < 4; ct++) {
            acc[ct] = (float4v){0.f, 0.f, 0.f, 0.f};
            const short8* bp = (const short8*)(Bs + (ct * 16 + m16) * 136);
#pragma unroll
            for (int kf = 0; kf < 4; kf++) {
                short8 b = bp[quad + kf * 4];
                acc[ct] = __builtin_amdgcn_mfma_f32_16x16x32_bf16(a[kf], b, acc[ct], 0, 0, 0);
            }
        }
        __syncthreads();   // all LDS reads landed; next iter may overwrite Bs

#pragma unroll
        for (int ct = 0; ct < 4; ct++) {
            int col = tile_n + ct * 16 + m16;
            int tbl = col >> nshift;
            int cc = col & cmask;
            size_t base = ((size_t)tbl * M) << nshift;
#pragma unroll
            for (int rg = 0; rg < 4; rg++) {
                int rr = tile_m + w * 16 + quad * 4 + rg;
                if (rr < M) C[base + (((size_t)rr) << nshift) + cc] = (_Float16)acc[ct][rg];
            }
        }
    }
}

__launch_bounds__(256)
__global__ void gemm_kernel(const __hip_bfloat16* __restrict__ A,
                            const __hip_bfloat16* __restrict__ Bt,
                            _Float16* __restrict__ C,
                            int M, int nshift, int tilesPerSplit) {
    gemm_body(A, Bt, C, M, nshift, blockIdx.x * 64,
              blockIdx.y * tilesPerSplit, blockIdx.y * tilesPerSplit + tilesPerSplit,
              threadIdx.x);
}

// ---------------- merged work1: GEMM1 (blocks [0,782)) + 2-pass scatter ----------------
// R11: GEMM1 y-split 3->1 (A-panel read once, longer GEMM blocks overlap more
// scatter); scatter passes 4->2 (curs window 300 KB still L2-resident; halves the
// redundant src/dst re-reads). List contents unchanged: each dst is in exactly one
// window; intra-list order is atomic-arrival order (arbitrary, as before).

__launch_bounds__(256)
__global__ void work1_kernel(const __hip_bfloat16* __restrict__ A,
                             const __hip_bfloat16* __restrict__ Bt,
                             _Float16* __restrict__ C,
                             const int* __restrict__ src, const int* __restrict__ dst,
                             int* __restrict__ curs, int* __restrict__ esrc) {
    int wg = blockIdx.x;
    if (wg < 782) {   // GEMM1: 782 tiles, all 12 n-tiles per block, nshift=7
        gemm_body(A, Bt, C, NN, 7, wg * 64, 0, 12, threadIdx.x);
    } else {
        int wg2 = wg - 782;           // 0..12287 = 6144 x 2 passes
        int p = wg2 >> 13;            // wg2 / 6144 -> need exact: 6144 = 0x1800, use div
        p = wg2 / 6144;
        int i = (wg2 - p * 6144) * 256 + threadIdx.x;
        int d = dst[i];
        if ((unsigned)(d - p * 25000) < 25000u) {
            int r = i >> ESHIFT;
            int pos = atomicAdd(&curs[r * NN + d], 1);
            esrc[pos] = src[i] << 8;
        }
    }
}

// ---------------- fused per-node softmax + aggregation ----------------
// R8's proven structure (agg_L2 127.5 µs, VGPR 48): one wave per node; 2 edge-halves
// x 32 channel-slices; interleaved slot pairs + short tail (main loop mask-free);
// DPP-only 8-lane score reduce; f16 tables (packed math + fdot2), f32 accumulate.
// NO min-waves launch bound (R5: pinning forced 32 VGPR -> 300 MB spill). R10
// established agg is at its memory roofline (805 MB compulsory gather @ 6.3 TB/s
// L2-delivered; occupancy-null at 58%): do not touch.

template <int W2>
__device__ inline void ldrow16(const char* __restrict__ p, half2v* hv) {
    if constexpr (W2 == 2) {   // 4 ch: 8 bytes
        uint2 pk = *(const uint2*)p;
        hv[0] = __builtin_bit_cast(half2v, pk.x);
        hv[1] = __builtin_bit_cast(half2v, pk.y);
    } else {                   // 8 ch: 16 bytes
        uint4 pk = *(const uint4*)p;
        hv[0] = __builtin_bit_cast(half2v, pk.x);
        hv[1] = __builtin_bit_cast(half2v, pk.y);
        hv[2] = __builtin_bit_cast(half2v, pk.z);
        hv[3] = __builtin_bit_cast(half2v, pk.w);
    }
}

template <int W2>
__device__ inline float edot16(const half2v* hv, const half2v* hdv, const half2v* al) {
    const half2v c02 = {(_Float16)0.2f, (_Float16)0.2f};
    float s = 0.f;
#pragma unroll
    for (int j = 0; j < W2; j++) {
        half2v m = hv[j] + hdv[j];                         // v_pk_add_f16
        half2v lr = __builtin_elementwise_max(m, m * c02); // v_pk_mul + v_pk_max
#if USE_FDOT2
        s = __builtin_amdgcn_fdot2(lr, al[j], s, false);   // v_dot2_f32_f16
#else
        half2v tt = lr * al[j];
        s += (float)tt.x + (float)tt.y;
#endif
    }
    return s;
}

template <int CTRL>
__device__ inline float dpp_add(float s) {
    int t = __builtin_amdgcn_update_dpp(0, __float_as_int(s), CTRL, 0xF, 0xF, true);
    return s + __int_as_float(t);
}

__device__ inline float hred8(float s) {
    s = dpp_add<0xB1>(s);
    s = dpp_add<0x4E>(s);
    s = dpp_add<0x141>(s);
    return s;
}

template <int W2, bool L1, int SH>
__launch_bounds__(256)
__global__ void agg_kernel(const char* __restrict__ C,               // f16 tables, byte-addressed
                           const float* __restrict__ a,              // [R][NC]
                           const int* __restrict__ offs, const int* __restrict__ deg,
                           const int* __restrict__ esrc,             // byte offsets (src<<8)
                           float* __restrict__ outf, __hip_bfloat16* __restrict__ outb) {
    const int V = 2 * W2;
    const int NC = 32 * V;
    const int ROWB = NC * 2;                          // row bytes
    int wid = (blockIdx.x * 256 + threadIdx.x) >> 6;  // node id, < 50000 exact
    int lane = threadIdx.x & 63;
    int g = lane >> 5;
    int c = lane & 31;
    int eb = c * V;            // channel offset
    int ebb = eb * 2;          // byte offset within row
    int kb = g << 1;           // interleaved-pair base: half g owns {kb, kb+1, kb+4, kb+5}

    float2v total[W2];
#pragma unroll
    for (int j = 0; j < W2; j++) total[j] = (float2v){0.f, 0.f};

#pragma unroll 1
    for (int r = 0; r < RR; r++) {
        const char* hsb = C + (size_t)(2 * r) * NN * ROWB + ebb;
        const char* hdb = C + (size_t)(2 * r + 1) * NN * ROWB + ebb;
        half2v hdv[W2], al[W2];
        float2v acc[W2];
        ldrow16<W2>(hdb + (size_t)wid * ROWB, hdv);
#pragma unroll
        for (int j = 0; j < W2; j++) {
            al[j] = (half2v){(_Float16)(a[r * NC + eb + 2 * j] * LOG2E),
                             (_Float16)(a[r * NC + eb + 2 * j + 1] * LOG2E)};
            acc[j] = (float2v){0.f, 0.f};
        }
        float den = 0.f;
        int e0 = offs[r * NN + wid];
        int dg = deg[r * NN + wid];
        int elast = e0 + ((dg > 0) ? dg : 1) - 1;
        int nfull = dg >> 3;
        int rem = dg & 7;
        int u0 = esrc[min(e0 + kb,     elast)];
        int u1 = esrc[min(e0 + kb + 1, elast)];
        int u2 = esrc[min(e0 + kb + 4, elast)];
        int u3 = esrc[min(e0 + kb + 5, elast)];
        for (int it = 0; it < nfull; ++it) {
            int kn = (it << 3) + 8;
            int n0 = esrc[min(e0 + kn + kb,     elast)];
            int n1 = esrc[min(e0 + kn + kb + 1, elast)];
            int n2 = esrc[min(e0 + kn + kb + 4, elast)];
            int n3 = esrc[min(e0 + kn + kb + 5, elast)];
            half2v hv0[W2], hv1[W2], hv2[W2], hv3[W2];
            ldrow16<W2>(hsb + ((size_t)(unsigned)u0 << SH), hv0);
            ldrow16<W2>(hsb + ((size_t)(unsigned)u1 << SH), hv1);
            ldrow16<W2>(hsb + ((size_t)(unsigned)u2 << SH), hv2);
            ldrow16<W2>(hsb + ((size_t)(unsigned)u3 << SH), hv3);
            float p0 = __builtin_amdgcn_exp2f(hred8(edot16<W2>(hv0, hdv, al)));
            float p1 = __builtin_amdgcn_exp2f(hred8(edot16<W2>(hv1, hdv, al)));
            float p2 = __builtin_amdgcn_exp2f(hred8(edot16<W2>(hv2, hdv, al)));
            float p3 = __builtin_amdgcn_exp2f(hred8(edot16<W2>(hv3, hdv, al)));
            den += (p0 + p1) + (p2 + p3);
#pragma unroll
            for (int j = 0; j < W2; j++) {
                acc[j].x = __builtin_fmaf(p0, (float)hv0[j].x, acc[j].x);
                acc[j].y = __builtin_fmaf(p0, (float)hv0[j].y, acc[j].y);
                acc[j].x = __builtin_fmaf(p1, (float)hv1[j].x, acc[j].x);
                acc[j].y = __builtin_fmaf(p1, (float)hv1[j].y, acc[j].y);
                acc[j].x = __builtin_fmaf(p2, (float)hv2[j].x, acc[j].x);
                acc[j].y = __builtin_fmaf(p2, (float)hv2[j].y, acc[j].y);
                acc[j].x = __builtin_fmaf(p3, (float)hv3[j].x, acc[j].x);
                acc[j].y = __builtin_fmaf(p3, (float)hv3[j].y, acc[j].y);
            }
            u0 = n0; u1 = n1; u2 = n2; u3 = n3;
        }
        if (rem) {
            if (rem <= 4) {
                half2v hv0[W2], hv1[W2];
                ldrow16<W2>(hsb + ((size_t)(unsigned)u0 << SH), hv0);
                ldrow16<W2>(hsb + ((size_t)(unsigned)u1 << SH), hv1);
                float s0 = hred8(edot16<W2>(hv0, hdv, al));
                float s1 = hred8(edot16<W2>(hv1, hdv, al));
                float p0 = (kb     < rem) ? __builtin_amdgcn_exp2f(s0) : 0.f;
                float p1 = (kb + 1 < rem) ? __builtin_amdgcn_exp2f(s1) : 0.f;
                den += p0 + p1;
#pragma unroll
                for (int j = 0; j < W2; j++) {
                    acc[j].x = __builtin_fmaf(p0, (float)hv0[j].x, acc[j].x);
                    acc[j].y = __builtin_fmaf(p0, (float)hv0[j].y, acc[j].y);
                    acc[j].x = __builtin_fmaf(p1, (float)hv1[j].x, acc[j].x);
                    acc[j].y = __builtin_fmaf(p1, (float)hv1[j].y, acc[j].y);
                }
            } else {
                half2v hv0[W2], hv1[W2], hv2[W2], hv3[W2];
                ldrow16<W2>(hsb + ((size_t)(unsigned)u0 << SH), hv0);
                ldrow16<W2>(hsb + ((size_t)(unsigned)u1 << SH), hv1);
                ldrow16<W2>(hsb + ((size_t)(unsigned)u2 << SH), hv2);
                ldrow16<W2>(hsb + ((size_t)(unsigned)u3 << SH), hv3);
                float s0 = hred8(edot16<W2>(hv0, hdv, al));
                float s1 = hred8(edot16<W2>(hv1, hdv, al));
                float s2 = hred8(edot16<W2>(hv2, hdv, al));
                float s3 = hred8(edot16<W2>(hv3, hdv, al));
                float p0 = (kb     < rem) ? __builtin_amdgcn_exp2f(s0) : 0.f;
                float p1 = (kb + 1 < rem) ? __builtin_amdgcn_exp2f(s1) : 0.f;
                float p2 = (kb + 4 < rem) ? __builtin_amdgcn_exp2f(s2) : 0.f;
                float p3 = (kb + 5 < rem) ? __builtin_amdgcn_exp2f(s3) : 0.f;
                den += (p0 + p1) + (p2 + p3);
#pragma unroll
                for (int j = 0; j < W2; j++) {
                    acc[j].x = __builtin_fmaf(p0, (float)hv0[j].x, acc[j].x);
                    acc[j].y = __builtin_fmaf(p0, (float)hv0[j].y, acc[j].y);
                    acc[j].x = __builtin_fmaf(p1, (float)hv1[j].x, acc[j].x);
                    acc[j].y = __builtin_fmaf(p1, (float)hv1[j].y, acc[j].y);
                    acc[j].x = __builtin_fmaf(p2, (float)hv2[j].x, acc[j].x);
                    acc[j].y = __builtin_fmaf(p2, (float)hv2[j].y, acc[j].y);
                    acc[j].x = __builtin_fmaf(p3, (float)hv3[j].x, acc[j].x);
                    acc[j].y = __builtin_fmaf(p3, (float)hv3[j].y, acc[j].y);
                }
            }
        }
        den += __shfl_xor(den, 32);
        float inv = 1.f / (den + 1e-9f);
        float2v iv = (float2v){inv, inv};
#pragma unroll
        for (int j = 0; j < W2; j++) {
            float2v tt = acc[j];
            tt.x += __shfl_xor(tt.x, 32);
            tt.y += __shfl_xor(tt.y, 32);
            total[j] += tt * iv;
        }
    }

    if (g == 0) {
        if constexpr (L1) {
#pragma unroll
            for (int j = 0; j < W2; j++) {
                float v0 = total[j].x, v1 = total[j].y;
                outb[(size_t)wid * NC + eb + 2 * j]     = __float2bfloat16(v0 > 0.f ? v0 : 0.f);
                outb[(size_t)wid * NC + eb + 2 * j + 1] = __float2bfloat16(v1 > 0.f ? v1 : 0.f);
            }
        } else {
#pragma unroll
            for (int j = 0; j < W2; j++) {
                outf[(size_t)wid * NC + eb + 2 * j]     = total[j].x;
                outf[(size_t)wid * NC + eb + 2 * j + 1] = total[j].y;
            }
        }
    }
}

// ---------------- launch ----------------

extern "C" void kernel_launch(void* const* d_in, const int* in_sizes, int n_in,
                              void* d_out, int out_size, void* d_ws, size_t ws_size,
                              hipStream_t stream) {
    const float* x   = (const float*)d_in[0];
    const int*   src = (const int*)d_in[1];
    const int*   dst = (const int*)d_in[2];
    const float* W1s = (const float*)d_in[3];
    const float* W1d = (const float*)d_in[4];
    const float* a1  = (const float*)d_in[5];
    const float* W2s = (const float*)d_in[6];
    const float* W2d = (const float*)d_in[7];
    const float* a2  = (const float*)d_in[8];

    char* ws = (char*)d_ws;
    size_t off = 0;
    auto alloc = [&](size_t bytes) -> void* {
        void* p = ws + off;
        off += (bytes + 255) & ~(size_t)255;
        return p;
    };
    __hip_bfloat16* xb = (__hip_bfloat16*)alloc((size_t)NN * 128 * 2);
    __hip_bfloat16* hb = (__hip_bfloat16*)alloc((size_t)NN * 128 * 2);
    _Float16*       Cb = (_Float16*)alloc((size_t)NN * 1536 * 2);  // 6 tables
    __hip_bfloat16* T1 = (__hip_bfloat16*)alloc((size_t)768 * 128 * 2);
    __hip_bfloat16* T2 = (__hip_bfloat16*)alloc((size_t)1536 * 128 * 2);
    int* deg  = (int*)alloc((size_t)TN * 4);
    int* offs = (int*)alloc((size_t)TN * 4);
    int* curs = (int*)alloc((size_t)TN * 4);
    int* esrc = (int*)alloc((size_t)RR * EE * 4);
    int* part = (int*)alloc(4096);

    float* outp = (float*)d_out;

    // 1) zero histograms
    hipMemsetAsync(deg, 0, (size_t)TN * 4, stream);

    // 2) merged prep: conv + 4 transposes + hist
    prep_kernel<<<13546, 256, 0, stream>>>(x, (short4v*)xb, W1s, W1d, W2s, W2d,
                                           T1, T2, dst, deg);

    // 3-5) CSR scan
    scan1_kernel<<<NCHUNK, 256, 0, stream>>>(deg, part);
    scan2_kernel<<<1, 1, 0, stream>>>(part);
    scan3_kernel<<<NCHUNK, 256, 0, stream>>>(deg, part, offs, curs);

    // 6) work1: GEMM1 (782 blocks, full N sweep) || 2-pass scatter (12288 blocks)
    work1_kernel<<<782 + 12288, 256, 0, stream>>>(xb, T1, Cb, src, dst, curs, esrc);

    // 7) agg layer 1 (fuses relu + bf16 cast -> hb)
    agg_kernel<2, true, 0><<<12500, 256, 0, stream>>>((const char*)Cb, a1, offs, deg, esrc,
                                                      nullptr, hb);

    // 8) GEMM2 [N,128]x[128,1536] -> 6 compact [N,256] f16 tables (2-way N split)
    gemm_kernel<<<dim3(782, 2), 256, 0, stream>>>(hb, T2, Cb, NN, 8, 12);

    // 9) agg layer 2 -> f32 d_out
    agg_kernel<4, false, 1><<<12500, 256, 0, stream>>>((const char*)Cb, a2, offs, deg, esrc,
                                                       outp, nullptr);
}